// Round 3
// baseline (3298.431 us; speedup 1.0000x reference)
//
#include <hip/hip_runtime.h>
#include <stdint.h>
#include <math.h>

#define T_STEPS 4
#define BB 32
#define NN 197
#define DD 512
#define DH 2048
#define RR (T_STEPS*BB*NN)          // 25216 rows, divisible by 64
#define RPT (BB*NN)                 // 6304

typedef unsigned short ushort_t;
typedef unsigned char u8;
typedef __attribute__((ext_vector_type(8))) short bf16x8;
typedef __attribute__((ext_vector_type(4))) float f32x4;
typedef __attribute__((ext_vector_type(4))) double f64x4;

__device__ __forceinline__ float bf2f(ushort_t h) {
    return __uint_as_float(((uint32_t)h) << 16);
}
__device__ __forceinline__ f32x4 mfma_bf16(bf16x8 a, bf16x8 b, f32x4 c) {
    return __builtin_amdgcn_mfma_f32_16x16x32_bf16(a, b, c, 0, 0, 0);
}
__device__ __forceinline__ f64x4 mfma64(double a, double b, f64x4 c) {
    return __builtin_amdgcn_mfma_f64_16x16x4f64(a, b, c, 0, 0, 0);
}

// ---------------------------------------------------------------------------
// LayerNorm (fp64).  One wave per (t,b,n) row; output row r' = (b*197+n)*4+t
// (bn-major, t-inner) so GEMM epilogues can run the LIF scan in-register.
// HAS_SP=1: input = x + spike_plane(u8, r'-layout).
// ---------------------------------------------------------------------------
template<int HAS_SP>
__global__ __launch_bounds__(64) void ln64_kernel(
    const float* __restrict__ xin, const u8* __restrict__ spp,
    const float* __restrict__ gw, const float* __restrict__ bw,
    double* __restrict__ yout)
{
    int id = blockIdx.x;                 // t-major row id
    int t = id / RPT;
    int rem = id % RPT;                  // b*197+n
    size_t rp = (size_t)rem * 4 + t;     // r' row
    int lane = threadIdx.x;

    const float* xp = xin + (size_t)id * DD + (size_t)lane * 8;
    float4 a = *(const float4*)xp;
    float4 bq = *(const float4*)(xp + 4);
    double v[8] = {a.x, a.y, a.z, a.w, bq.x, bq.y, bq.z, bq.w};
    if (HAS_SP) {
        const u8* sp8 = spp + rp * DD + (size_t)lane * 8;
#pragma unroll
        for (int i = 0; i < 8; ++i) v[i] += (double)sp8[i];
    }

    double s = 0.0;
#pragma unroll
    for (int i = 0; i < 8; ++i) s += v[i];
#pragma unroll
    for (int o = 32; o; o >>= 1) s += __shfl_xor(s, o, 64);
    double m = s * (1.0 / 512.0);

    double d[8], ss = 0.0;
#pragma unroll
    for (int i = 0; i < 8; ++i) { d[i] = v[i] - m; ss += d[i] * d[i]; }
#pragma unroll
    for (int o = 32; o; o >>= 1) ss += __shfl_xor(ss, o, 64);
    double rstd = 1.0 / sqrt(ss * (1.0 / 512.0) + 1e-5);

    float4 g1 = *(const float4*)(gw + lane * 8);
    float4 g2 = *(const float4*)(gw + lane * 8 + 4);
    float4 b1 = *(const float4*)(bw + lane * 8);
    float4 b2 = *(const float4*)(bw + lane * 8 + 4);
    double gg[8] = {g1.x, g1.y, g1.z, g1.w, g2.x, g2.y, g2.z, g2.w};
    double bb[8] = {b1.x, b1.y, b1.z, b1.w, b2.x, b2.y, b2.z, b2.w};

    double* yp = yout + rp * DD + (size_t)lane * 8;
#pragma unroll
    for (int i = 0; i < 8; ++i) yp[i] = d[i] * rstd * gg[i] + bb[i];
}

// ---------------------------------------------------------------------------
// fp64 MFMA GEMM: C[m,n] = sum_k A[m,k]*B[n,k] (+bias[n]) with fused LIF
// epilogue.  Rows are r'-layout (bn-major, t-inner) so each lane's 4 C regs
// are the T=4 sequence of one neuron.
// ASRC: 0 = fp64 A; 1 = bf16 hi/lo pair (exact); 2 = u8 binary.
// EPI:  0 = LIF -> u8 spike plane;  2 = LIF + residuals -> fp32 d_out.
// ---------------------------------------------------------------------------
template<int ASRC, int EPI>
__global__ __launch_bounds__(256) void gemm64_kernel(
    const double* __restrict__ A64,
    const ushort_t* __restrict__ Abh, const ushort_t* __restrict__ Abl,
    const u8* __restrict__ Au8,
    const float* __restrict__ Bw, const float* __restrict__ biasp,
    u8* __restrict__ spout, float* __restrict__ fout,
    const float* __restrict__ xres, const u8* __restrict__ spres,
    int M, int N, int K)
{
    __shared__ double As[64 * 33];
    __shared__ double Bs[64 * 33];

    int tid = threadIdx.x;
    int n0 = blockIdx.x * 64;
    int m0 = blockIdx.y * 64;
    int lane = tid & 63, wave = tid >> 6;
    int quad = lane >> 4, r16 = lane & 15;

    f64x4 acc[4];
#pragma unroll
    for (int c = 0; c < 4; ++c) acc[c] = (f64x4){0.0, 0.0, 0.0, 0.0};

    for (int k0 = 0; k0 < K; k0 += 32) {
        __syncthreads();
#pragma unroll
        for (int i = 0; i < 8; ++i) {
            int idx = i * 256 + tid;
            int row = idx >> 5, kk = idx & 31;
            size_t go = (size_t)(m0 + row) * K + k0 + kk;
            double av;
            if (ASRC == 0)      av = A64[go];
            else if (ASRC == 1) av = (double)bf2f(Abh[go]) + (double)bf2f(Abl[go]);
            else                av = (double)Au8[go];
            As[row * 33 + kk] = av;
            Bs[row * 33 + kk] = (double)Bw[(size_t)(n0 + row) * K + k0 + kk];
        }
        __syncthreads();

#pragma unroll
        for (int ks = 0; ks < 8; ++ks) {
            double a = As[(wave * 16 + r16) * 33 + ks * 4 + quad];
#pragma unroll
            for (int c = 0; c < 4; ++c) {
                double b = Bs[(c * 16 + r16) * 33 + ks * 4 + quad];
                acc[c] = mfma64(a, b, acc[c]);
            }
        }
    }

    int rbase = m0 + wave * 16 + quad * 4;      // multiple of 4; rows rbase+t
#pragma unroll
    for (int c = 0; c < 4; ++c) {
        int col = n0 + c * 16 + r16;
        double bv = biasp ? (double)biasp[col] : 0.0;
        double v = 0.0;
        if (EPI == 0) {
#pragma unroll
            for (int t = 0; t < T_STEPS; ++t) {
                double p = acc[c][t] + bv;
                v = v + (p - v) * 0.5;
                int s = (v >= 1.0);
                spout[(size_t)(rbase + t) * N + col] = (u8)s;
                if (s) v = 0.0;
            }
        } else {
            int bn = rbase >> 2;
            int b = bn / NN, n = bn % NN;
#pragma unroll
            for (int t = 0; t < T_STEPS; ++t) {
                double p = acc[c][t] + bv;
                v = v + (p - v) * 0.5;
                int s = (v >= 1.0);
                size_t oi = (((size_t)t * BB + b) * NN + n) * DD + col;
                double res = (double)xres[oi]
                           + (double)spres[(size_t)(rbase + t) * DD + col]
                           + (double)s;
                fout[oi] = (float)res;
                if (s) v = 0.0;
            }
        }
    }
}

// ---------------------------------------------------------------------------
// Attention per (t,b,h): out = Q (K^T V) / 8 — all inputs binary u8 spikes,
// every step integer-exact in bf16 MFMA / fp32 accum.  Output written as
// exact bf16 hi/lo pair (values are multiples of 1/8, < 2^14).
// ---------------------------------------------------------------------------
__global__ __launch_bounds__(256) void attn_kernel(
    const u8* __restrict__ qs, const u8* __restrict__ ks,
    const u8* __restrict__ vs,
    ushort_t* __restrict__ Ah, ushort_t* __restrict__ Al)
{
    __shared__ __align__(16) short sm[29696];
    short* Kt = sm;              // 64 x 232
    short* Vt = sm + 14848;      // 64 x 232
    short* MT = sm + 25088;      // 64 x 72 (aliases Vt tail, used after sync)
    short* Qsm = sm;             // 224 x 72 (aliases Kt/Vt, used after sync)

    int bid = blockIdx.x;
    int t = bid >> 8;
    int b = (bid >> 3) & 31;
    int h = bid & 7;
    // spike row for token n: r' = (b*197+n)*4 + t
    size_t base = ((size_t)(b * NN) * 4 + t) * DD + (size_t)h * 64;
    const size_t rstride = (size_t)4 * DD;

    int tid = threadIdx.x;
    int lane = tid & 63, wave = tid >> 6;
    int quad = lane >> 4, r16 = lane & 15;

    for (int i = tid; i < 224 * 16; i += 256) {
        int n = i >> 4;
        int d4 = (i & 15) * 4;
        short kv[4] = {0,0,0,0}, vv[4] = {0,0,0,0};
        if (n < NN) {
            uchar4 kq = *(const uchar4*)(ks + base + (size_t)n * rstride + d4);
            uchar4 vq = *(const uchar4*)(vs + base + (size_t)n * rstride + d4);
            kv[0] = kq.x ? (short)0x3F80 : 0; kv[1] = kq.y ? (short)0x3F80 : 0;
            kv[2] = kq.z ? (short)0x3F80 : 0; kv[3] = kq.w ? (short)0x3F80 : 0;
            vv[0] = vq.x ? (short)0x3F80 : 0; vv[1] = vq.y ? (short)0x3F80 : 0;
            vv[2] = vq.z ? (short)0x3F80 : 0; vv[3] = vq.w ? (short)0x3F80 : 0;
        }
#pragma unroll
        for (int j = 0; j < 4; ++j) {
            Kt[(d4 + j) * 232 + n] = kv[j];
            Vt[(d4 + j) * 232 + n] = vv[j];
        }
    }
    __syncthreads();

    // M = K^T V (64x64 over n padded to 224) — integer counts <= 197
    f32x4 accM[4];
#pragma unroll
    for (int c = 0; c < 4; ++c) accM[c] = (f32x4){0.f, 0.f, 0.f, 0.f};
#pragma unroll
    for (int kc = 0; kc < 7; ++kc) {
        int ko = kc * 32 + quad * 8;
        bf16x8 a = *(const bf16x8*)&Kt[(wave * 16 + r16) * 232 + ko];
#pragma unroll
        for (int c = 0; c < 4; ++c) {
            bf16x8 bfr = *(const bf16x8*)&Vt[(c * 16 + r16) * 232 + ko];
            accM[c] = mfma_bf16(a, bfr, accM[c]);
        }
    }
    __syncthreads();

    // store M transposed as bf16 (exact: integers <= 197 < 256)
#pragma unroll
    for (int c = 0; c < 4; ++c) {
#pragma unroll
        for (int reg = 0; reg < 4; ++reg) {
            int d1 = wave * 16 + quad * 4 + reg;
            int d2 = c * 16 + r16;
            MT[d2 * 72 + d1] = (short)(((uint32_t)__float_as_uint(accM[c][reg])) >> 16);
        }
    }
    for (int i = tid; i < 224 * 16; i += 256) {
        int n = i >> 4;
        int d4 = (i & 15) * 4;
        short qv[4] = {0,0,0,0};
        if (n < NN) {
            uchar4 qq = *(const uchar4*)(qs + base + (size_t)n * rstride + d4);
            qv[0] = qq.x ? (short)0x3F80 : 0; qv[1] = qq.y ? (short)0x3F80 : 0;
            qv[2] = qq.z ? (short)0x3F80 : 0; qv[3] = qq.w ? (short)0x3F80 : 0;
        }
        Qsm[n * 72 + d4 + 0] = qv[0];
        Qsm[n * 72 + d4 + 1] = qv[1];
        Qsm[n * 72 + d4 + 2] = qv[2];
        Qsm[n * 72 + d4 + 3] = qv[3];
    }
    __syncthreads();

    for (int rt = wave; rt < 14; rt += 4) {
        f32x4 acc[4];
#pragma unroll
        for (int c = 0; c < 4; ++c) acc[c] = (f32x4){0.f, 0.f, 0.f, 0.f};
#pragma unroll
        for (int kc = 0; kc < 2; ++kc) {
            int ko = kc * 32 + quad * 8;
            bf16x8 a = *(const bf16x8*)&Qsm[(rt * 16 + r16) * 72 + ko];
#pragma unroll
            for (int c = 0; c < 4; ++c) {
                bf16x8 bfr = *(const bf16x8*)&MT[(c * 16 + r16) * 72 + ko];
                acc[c] = mfma_bf16(a, bfr, acc[c]);
            }
        }
#pragma unroll
        for (int c = 0; c < 4; ++c) {
#pragma unroll
            for (int reg = 0; reg < 4; ++reg) {
                int n = rt * 16 + quad * 4 + reg;
                if (n < NN) {
                    float val = acc[c][reg] * 0.125f;      // exact
                    uint32_t ub = __float_as_uint(val);
                    ushort_t hv = (ushort_t)(ub >> 16);    // truncate: hi part
                    float lo = val - bf2f(hv);             // exact residual
                    size_t off = base + (size_t)n * rstride + c * 16 + r16;
                    Ah[off] = hv;
                    Al[off] = (ushort_t)(__float_as_uint(lo) >> 16);
                }
            }
        }
    }
}

// ---------------------------------------------------------------------------
extern "C" void kernel_launch(void* const* d_in, const int* in_sizes, int n_in,
                              void* d_out, int out_size, void* d_ws, size_t ws_size,
                              hipStream_t stream)
{
    const float* x      = (const float*)d_in[0];
    const float* ln1_g  = (const float*)d_in[1];
    const float* ln1_b  = (const float*)d_in[2];
    const float* wq     = (const float*)d_in[3];
    const float* wk     = (const float*)d_in[4];
    const float* wv     = (const float*)d_in[5];
    const float* proj_w = (const float*)d_in[6];
    const float* proj_b = (const float*)d_in[7];
    const float* ln2_g  = (const float*)d_in[8];
    const float* ln2_b  = (const float*)d_in[9];
    const float* fc1_w  = (const float*)d_in[10];
    const float* fc1_b  = (const float*)d_in[11];
    const float* fc2_w  = (const float*)d_in[12];
    const float* fc2_b  = (const float*)d_in[13];
    float* outp = (float*)d_out;

    // ws plan, S = 25,821,184 B; peak 7.5S = 193.7 MB
    // [0,4S): y64            then  sp u8 @0 (0.5S)
    // [1S,5S): y2_64 (after qkv spikes dead)
    // [4S,5.5S): q/k/v u8    [5.5S,7.5S): Ah/Al bf16
    // [5S,7S): h u8 (after Ah/Al dead)
    const size_t S = 25821184;
    char* wsb = (char*)d_ws;
    double*   y64 = (double*)(wsb);
    u8*       qs  = (u8*)(wsb + 4 * S);
    u8*       ksp = (u8*)(wsb + 4 * S + S / 2);
    u8*       vsp = (u8*)(wsb + 5 * S);
    ushort_t* Ah  = (ushort_t*)(wsb + 5 * S + S / 2);
    ushort_t* Al  = (ushort_t*)(wsb + 6 * S + S / 2);
    u8*       sp  = (u8*)(wsb);
    double*   y2  = (double*)(wsb + 1 * S);
    u8*       hsp = (u8*)(wsb + 5 * S);

    dim3 g8(8, RR / 64), g32(DH / 64, RR / 64);

    // 1. LN1 -> y64 (r'-layout)
    ln64_kernel<0><<<RR, 64, 0, stream>>>(x, nullptr, ln1_g, ln1_b, y64);

    // 2. q/k/v GEMMs (fp64 MFMA) with fused LIF -> u8 spike planes
    gemm64_kernel<0,0><<<g8, 256, 0, stream>>>(y64, nullptr, nullptr, nullptr,
        wq, nullptr, qs, nullptr, nullptr, nullptr, RR, DD, DD);
    gemm64_kernel<0,0><<<g8, 256, 0, stream>>>(y64, nullptr, nullptr, nullptr,
        wk, nullptr, ksp, nullptr, nullptr, nullptr, RR, DD, DD);
    gemm64_kernel<0,0><<<g8, 256, 0, stream>>>(y64, nullptr, nullptr, nullptr,
        wv, nullptr, vsp, nullptr, nullptr, nullptr, RR, DD, DD);

    // 3. linear attention (exact), bf16 hi/lo output
    attn_kernel<<<T_STEPS * BB * 8, 256, 0, stream>>>(qs, ksp, vsp, Ah, Al);

    // 4. proj GEMM + LIF -> sp
    gemm64_kernel<1,0><<<g8, 256, 0, stream>>>(nullptr, Ah, Al, nullptr,
        proj_w, proj_b, sp, nullptr, nullptr, nullptr, RR, DD, DD);

    // 5. LN2 of (x + sp) -> y2
    ln64_kernel<1><<<RR, 64, 0, stream>>>(x, sp, ln2_g, ln2_b, y2);

    // 6. fc1 GEMM + LIF -> h spikes
    gemm64_kernel<0,0><<<g32, 256, 0, stream>>>(y2, nullptr, nullptr, nullptr,
        fc1_w, fc1_b, hsp, nullptr, nullptr, nullptr, RR, DH, DD);

    // 7. fc2 GEMM + LIF + residuals -> fp32 output
    gemm64_kernel<2,2><<<g8, 256, 0, stream>>>(nullptr, nullptr, nullptr, hsp,
        fc2_w, fc2_b, nullptr, outp, x, sp, RR, DD, DH);
}

// Round 4
// 1073.892 us; speedup vs baseline: 3.0715x; 3.0715x over previous
//
#include <hip/hip_runtime.h>
#include <stdint.h>
#include <math.h>

#define T_STEPS 4
#define BB 32
#define NN 197
#define DD 512
#define DH 2048
#define RR (T_STEPS*BB*NN)          // 25216 rows (r'-layout: bn*4+t), /128 = 197
#define RPT (BB*NN)                 // 6304
#define LCAP 131072u

typedef unsigned short ushort_t;
typedef unsigned char u8;
typedef __attribute__((ext_vector_type(8))) short bf16x8;
typedef __attribute__((ext_vector_type(4))) float f32x4;

__device__ __forceinline__ float bf2f(ushort_t h) {
    return __uint_as_float(((uint32_t)h) << 16);
}
__device__ __forceinline__ ushort_t f2bf(float f) {
    uint32_t u = __float_as_uint(f);
    uint32_t r = (u + 0x7fffu + ((u >> 16) & 1u)) >> 16;
    return (ushort_t)r;
}
__device__ __forceinline__ f32x4 mfma_bf16(bf16x8 a, bf16x8 b, f32x4 c) {
    return __builtin_amdgcn_mfma_f32_16x16x32_bf16(a, b, c, 0, 0, 0);
}
// async global->LDS, 16B per lane. LDS dest = wave-uniform base + lane*16.
__device__ __forceinline__ void gll16(const void* gptr, void* lptr) {
    __builtin_amdgcn_global_load_lds(
        (const __attribute__((address_space(1))) uint32_t*)(uintptr_t)gptr,
        (__attribute__((address_space(3))) uint32_t*)(uintptr_t)lptr,
        16, 0, 0);
}
__device__ __forceinline__ double wred(double x) {
#pragma unroll
    for (int o = 32; o; o >>= 1) x += __shfl_xor(x, o, 64);
    return x;
}

// ---------------------------------------------------------------------------
// zero the suspect counters
// ---------------------------------------------------------------------------
__global__ void zero_kernel(uint32_t* p) {
    if (threadIdx.x < 8) p[threadIdx.x] = 0;
}

// ---------------------------------------------------------------------------
// weight pre-split fp32 -> 2 (or 3) bf16 planes, round-to-nearest (exact sum)
// ---------------------------------------------------------------------------
__global__ __launch_bounds__(256) void wsplit2(const float* __restrict__ w,
    ushort_t* __restrict__ w0, ushort_t* __restrict__ w1, int n) {
    int i = blockIdx.x * 256 + threadIdx.x;
    if (i >= n) return;
    float v = w[i];
    ushort_t h0 = f2bf(v);
    w0[i] = h0;
    w1[i] = f2bf(v - bf2f(h0));
}
__global__ __launch_bounds__(256) void wsplit3(const float* __restrict__ w,
    ushort_t* __restrict__ w0, ushort_t* __restrict__ w1,
    ushort_t* __restrict__ w2, int n) {
    int i = blockIdx.x * 256 + threadIdx.x;
    if (i >= n) return;
    float v = w[i];
    ushort_t h0 = f2bf(v);  float r1 = v - bf2f(h0);
    ushort_t h1 = f2bf(r1); float r2 = r1 - bf2f(h1);
    w0[i] = h0; w1[i] = h1; w2[i] = f2bf(r2);
}

// ---------------------------------------------------------------------------
// LayerNorm (fp64 internal) -> 2-way bf16 split, r'-layout rows (bn*4+t).
// HAS_SP=1: input = x + u8 spike plane (r'-layout).
// ---------------------------------------------------------------------------
template<int HAS_SP>
__global__ __launch_bounds__(64) void ln_split(
    const float* __restrict__ xin, const u8* __restrict__ spp,
    const float* __restrict__ gw, const float* __restrict__ bw,
    ushort_t* __restrict__ y0, ushort_t* __restrict__ y1)
{
    int id = blockIdx.x;                 // t-major row id
    int t = id / RPT, rem = id % RPT;
    size_t rp = (size_t)rem * 4 + t;
    int lane = threadIdx.x;

    const float* xp = xin + (size_t)id * DD + (size_t)lane * 8;
    float4 a = *(const float4*)xp;
    float4 bq = *(const float4*)(xp + 4);
    double v[8] = {a.x, a.y, a.z, a.w, bq.x, bq.y, bq.z, bq.w};
    if (HAS_SP) {
        const u8* sp8 = spp + rp * DD + (size_t)lane * 8;
#pragma unroll
        for (int i = 0; i < 8; ++i) v[i] += (double)sp8[i];
    }

    double s = 0.0;
#pragma unroll
    for (int i = 0; i < 8; ++i) s += v[i];
    s = wred(s);
    double m = s * (1.0 / 512.0);
    double d[8], ss = 0.0;
#pragma unroll
    for (int i = 0; i < 8; ++i) { d[i] = v[i] - m; ss += d[i] * d[i]; }
    ss = wred(ss);
    double rstd = 1.0 / sqrt(ss * (1.0 / 512.0) + 1e-5);

    float4 g1 = *(const float4*)(gw + lane * 8);
    float4 g2 = *(const float4*)(gw + lane * 8 + 4);
    float4 b1 = *(const float4*)(bw + lane * 8);
    float4 b2 = *(const float4*)(bw + lane * 8 + 4);
    double gg[8] = {g1.x, g1.y, g1.z, g1.w, g2.x, g2.y, g2.z, g2.w};
    double bb[8] = {b1.x, b1.y, b1.z, b1.w, b2.x, b2.y, b2.z, b2.w};

    bf16x8 o0, o1;
#pragma unroll
    for (int i = 0; i < 8; ++i) {
        float y = (float)(d[i] * rstd * gg[i] + bb[i]);
        ushort_t h0 = f2bf(y);
        o0[i] = (short)h0;
        o1[i] = (short)f2bf(y - bf2f(h0));
    }
    *(bf16x8*)(y0 + rp * DD + lane * 8) = o0;
    *(bf16x8*)(y1 + rp * DD + lane * 8) = o1;
}

// ---------------------------------------------------------------------------
// Split-bf16 GEMM, 128x128 tile, BK=64, 4 waves, global_load_lds staging.
// C[m,n] = sum_k A[m,k]*B[n,k] (+bias), fused LIF epilogue + suspect list.
// NSA: bf16 A planes (2, or 1 if AU8).  NSB: bf16 B planes (2 or 3).
// AU8: A is u8 binary, staged via VALU convert.  EPI: 0=u8 spikes, 2=fp32 out.
// ---------------------------------------------------------------------------
template<int NSA, int NSB, int AU8, int EPI>
__global__ __launch_bounds__(256) void gemm128(
    const ushort_t* __restrict__ A0p, const ushort_t* __restrict__ A1p,
    const u8* __restrict__ A8p,
    const ushort_t* __restrict__ B0p, const ushort_t* __restrict__ B1p,
    const ushort_t* __restrict__ B2p,
    const float* __restrict__ biasp, int N, int K, float delta,
    u8* __restrict__ spout, float* __restrict__ fout,
    const float* __restrict__ xres, const u8* __restrict__ spres,
    uint32_t* __restrict__ cnt, uint32_t* __restrict__ list)
{
    __shared__ short lds[(NSA + NSB) * 8192];

    int tid = threadIdx.x, lane = tid & 63, wave = tid >> 6;
    int quad = lane >> 4, r16 = lane & 15;
    int n0 = blockIdx.x * 128, m0 = blockIdx.y * 128;
    int wm = (wave & 1) * 64, wn = (wave >> 1) * 64;

    const ushort_t* Aps[2] = {A0p, A1p};
    const ushort_t* Bps[3] = {B0p, B1p, B2p};

    f32x4 acc[4][4];
#pragma unroll
    for (int rt = 0; rt < 4; ++rt)
#pragma unroll
        for (int ct = 0; ct < 4; ++ct) acc[rt][ct] = (f32x4){0.f,0.f,0.f,0.f};

    for (int k0 = 0; k0 < K; k0 += 64) {
        __syncthreads();
        if (AU8) {
#pragma unroll
            for (int i = 0; i < 2; ++i) {
                int g = i * 256 + tid;          // 512 groups of 16 elems
                int row = g >> 2, kc = (g & 3) * 16;
                const u8* src = A8p + (size_t)(m0 + row) * K + k0 + kc;
                uint4 raw = *(const uint4*)src;
                uint32_t wsr[4] = {raw.x, raw.y, raw.z, raw.w};
                short tmp[16];
#pragma unroll
                for (int j = 0; j < 4; ++j)
#pragma unroll
                    for (int bp = 0; bp < 4; ++bp)
                        tmp[j*4+bp] = ((wsr[j] >> (8*bp)) & 0xFFu) ? (short)0x3F80 : (short)0;
                *(bf16x8*)&lds[row * 64 + kc]     = *(bf16x8*)&tmp[0];
                *(bf16x8*)&lds[row * 64 + kc + 8] = *(bf16x8*)&tmp[8];
            }
        } else {
#pragma unroll
            for (int p = 0; p < NSA; ++p)
#pragma unroll
                for (int i = 0; i < 4; ++i) {
                    int c = i * 4 + wave;       // chunk 0..15 (1 KiB each)
                    int row = c * 8 + (lane >> 3);
                    int kc = (lane & 7) * 8;
                    gll16(Aps[p] + (size_t)(m0 + row) * K + k0 + kc,
                          &lds[p * 8192 + c * 512]);
                }
        }
#pragma unroll
        for (int q = 0; q < NSB; ++q)
#pragma unroll
            for (int i = 0; i < 4; ++i) {
                int c = i * 4 + wave;
                int row = c * 8 + (lane >> 3);
                int kc = (lane & 7) * 8;
                gll16(Bps[q] + (size_t)(n0 + row) * K + k0 + kc,
                      &lds[(NSA + q) * 8192 + c * 512]);
            }
        __syncthreads();

#pragma unroll
        for (int sub = 0; sub < 2; ++sub) {
            const int ko = sub * 32 + quad * 8;
            bf16x8 af[4][2], bfv[4][3];
#pragma unroll
            for (int rt = 0; rt < 4; ++rt)
#pragma unroll
                for (int p = 0; p < NSA; ++p)
                    af[rt][p] = *(const bf16x8*)&lds[p * 8192 + (wm + rt*16 + r16) * 64 + ko];
#pragma unroll
            for (int ct = 0; ct < 4; ++ct)
#pragma unroll
                for (int q = 0; q < NSB; ++q)
                    bfv[ct][q] = *(const bf16x8*)&lds[(NSA + q) * 8192 + (wn + ct*16 + r16) * 64 + ko];
#pragma unroll
            for (int rt = 0; rt < 4; ++rt)
#pragma unroll
                for (int ct = 0; ct < 4; ++ct) {
                    f32x4 a = acc[rt][ct];
                    if (NSA == 2)             a = mfma_bf16(af[rt][1], bfv[ct][1], a);
                    if (NSA == 2)             a = mfma_bf16(af[rt][1], bfv[ct][0], a);
                    if (NSB == 3)             a = mfma_bf16(af[rt][0], bfv[ct][2], a);
                    a = mfma_bf16(af[rt][0], bfv[ct][1], a);
                    a = mfma_bf16(af[rt][0], bfv[ct][0], a);
                    acc[rt][ct] = a;
                }
        }
    }

    // epilogue: each lane owns T=4 of 16 neurons (r'-layout rows)
#pragma unroll
    for (int rt = 0; rt < 4; ++rt) {
        int rbase = m0 + wm + rt * 16 + quad * 4;   // multiple of 4
        int bn = rbase >> 2;
#pragma unroll
        for (int ct = 0; ct < 4; ++ct) {
            int col = n0 + wn + ct * 16 + r16;
            float bv = biasp ? biasp[col] : 0.0f;
            float v = 0.f;
            bool nearf = false;
#pragma unroll
            for (int t = 0; t < 4; ++t) {
                float p = acc[rt][ct][t] + bv;
                v = v + (p - v) * 0.5f;
                nearf |= (fabsf(v - 1.0f) < delta);
                int s = (v >= 1.0f);
                if (EPI == 0) {
                    spout[(size_t)(rbase + t) * N + col] = (u8)s;
                } else {
                    int b = bn / NN, n = bn % NN;
                    size_t oi = (((size_t)t * BB + b) * NN + n) * DD + col;
                    fout[oi] = (float)((double)xres[oi]
                             + (double)spres[(size_t)(rbase + t) * DD + col]
                             + (double)s);
                }
                if (s) v = 0.f;
            }
            if (nearf) {
                uint32_t idx = atomicAdd(cnt, 1u);
                if (idx < LCAP) list[idx] = (uint32_t)bn * (uint32_t)N + (uint32_t)col;
            }
        }
    }
}

// ---------------------------------------------------------------------------
// fp64 refinement of flagged neurons (one wave per neuron).
// ASRC 0: A = LayerNorm(x [+ sp]) recomputed in fp64 (K=512)
// ASRC 1: A = Ah+Al exact bf16 pair (K=512)
// Rewrites the 4 u8 spike entries of the neuron.
// ---------------------------------------------------------------------------
template<int ASRC>
__global__ __launch_bounds__(256) void refine_spike(
    const uint32_t* __restrict__ cnt, const uint32_t* __restrict__ list,
    const float* __restrict__ xin, const u8* __restrict__ spres,
    const ushort_t* __restrict__ Ah, const ushort_t* __restrict__ Al,
    const float* __restrict__ lng, const float* __restrict__ lnb,
    const float* __restrict__ W, const float* __restrict__ biasp,
    int N, u8* __restrict__ spout)
{
    int lane = threadIdx.x & 63;
    int wid = (blockIdx.x * 256 + threadIdx.x) >> 6;
    int nw = (gridDim.x * 256) >> 6;
    uint32_t nsus = *cnt; if (nsus > LCAP) nsus = LCAP;
    for (uint32_t i = wid; i < nsus; i += nw) {
        uint32_t id = list[i];
        int col = (int)(id % (uint32_t)N);
        int bn  = (int)(id / (uint32_t)N);
        double p[4];
#pragma unroll
        for (int t = 0; t < 4; ++t) {
            size_t rp = (size_t)bn * 4 + t;
            double dot = 0.0;
            if (ASRC == 0) {
                const float* xr = xin + ((size_t)t * RPT + bn) * DD;
                const u8* sr = spres ? (spres + rp * DD) : (const u8*)nullptr;
                double xv[8], s = 0.0;
#pragma unroll
                for (int j = 0; j < 8; ++j) {
                    int k = j * 64 + lane;
                    double val = (double)xr[k];
                    if (spres) val += (double)sr[k];
                    xv[j] = val; s += val;
                }
                s = wred(s);
                double m = s * (1.0 / 512.0), ss = 0.0;
#pragma unroll
                for (int j = 0; j < 8; ++j) { double d = xv[j] - m; ss += d * d; }
                ss = wred(ss);
                double rstd = 1.0 / sqrt(ss * (1.0 / 512.0) + 1e-5);
#pragma unroll
                for (int j = 0; j < 8; ++j) {
                    int k = j * 64 + lane;
                    double y = (xv[j] - m) * rstd * (double)lng[k] + (double)lnb[k];
                    dot += y * (double)W[(size_t)col * DD + k];
                }
            } else {
#pragma unroll
                for (int j = 0; j < 8; ++j) {
                    int k = j * 64 + lane;
                    double av = (double)bf2f(Ah[rp * DD + k]) + (double)bf2f(Al[rp * DD + k]);
                    dot += av * (double)W[(size_t)col * DD + k];
                }
            }
            dot = wred(dot);
            p[t] = dot + (biasp ? (double)biasp[col] : 0.0);
        }
        if (lane == 0) {
            double v = 0.0;
#pragma unroll
            for (int t = 0; t < 4; ++t) {
                v = v + (p[t] - v) * 0.5;
                int s = (v >= 1.0);
                spout[(size_t)(bn * 4 + t) * N + col] = (u8)s;
                if (s) v = 0.0;
            }
        }
    }
}

// fc2 refinement: A = u8 h (K=2048), rewrites fp32 outputs with residuals
__global__ __launch_bounds__(256) void refine_out(
    const uint32_t* __restrict__ cnt, const uint32_t* __restrict__ list,
    const u8* __restrict__ hsp, const float* __restrict__ W,
    const float* __restrict__ biasp,
    const float* __restrict__ xin, const u8* __restrict__ spres,
    float* __restrict__ fout)
{
    int lane = threadIdx.x & 63;
    int wid = (blockIdx.x * 256 + threadIdx.x) >> 6;
    int nw = (gridDim.x * 256) >> 6;
    uint32_t nsus = *cnt; if (nsus > LCAP) nsus = LCAP;
    for (uint32_t i = wid; i < nsus; i += nw) {
        uint32_t id = list[i];
        int col = (int)(id % (uint32_t)DD);
        int bn  = (int)(id / (uint32_t)DD);
        double p[4];
#pragma unroll
        for (int t = 0; t < 4; ++t) {
            size_t rp = (size_t)bn * 4 + t;
            double dot = 0.0;
#pragma unroll
            for (int j = 0; j < 32; ++j) {
                int k = j * 64 + lane;
                dot += (double)hsp[rp * DH + k] * (double)W[(size_t)col * DH + k];
            }
            dot = wred(dot);
            p[t] = dot + (double)biasp[col];
        }
        if (lane == 0) {
            int b = bn / NN, n = bn % NN;
            double v = 0.0;
#pragma unroll
            for (int t = 0; t < 4; ++t) {
                v = v + (p[t] - v) * 0.5;
                int s = (v >= 1.0);
                size_t oi = (((size_t)t * BB + b) * NN + n) * DD + col;
                fout[oi] = (float)((double)xin[oi]
                         + (double)spres[(size_t)(bn * 4 + t) * DD + col]
                         + (double)s);
                if (s) v = 0.0;
            }
        }
    }
}

// ---------------------------------------------------------------------------
// Attention per (t,b,h): out = Q (K^T V) / 8 — binary u8 spikes, integer-
// exact in bf16 MFMA/fp32.  Output = exact bf16 hi/lo pair (m < 2^14).
// ---------------------------------------------------------------------------
__global__ __launch_bounds__(256) void attn_kernel(
    const u8* __restrict__ qs, const u8* __restrict__ ks,
    const u8* __restrict__ vs,
    ushort_t* __restrict__ Ah, ushort_t* __restrict__ Al)
{
    __shared__ __align__(16) short sm[29696];
    short* Kt = sm;              // 64 x 232
    short* Vt = sm + 14848;      // 64 x 232
    short* MT = sm + 25088;      // 64 x 72
    short* Qsm = sm;             // 224 x 72

    int bid = blockIdx.x;
    int t = bid >> 8;
    int b = (bid >> 3) & 31;
    int h = bid & 7;
    size_t base = ((size_t)(b * NN) * 4 + t) * DD + (size_t)h * 64;
    const size_t rstride = (size_t)4 * DD;

    int tid = threadIdx.x;
    int lane = tid & 63, wave = tid >> 6;
    int quad = lane >> 4, r16 = lane & 15;

    for (int i = tid; i < 224 * 16; i += 256) {
        int n = i >> 4;
        int d4 = (i & 15) * 4;
        short kv[4] = {0,0,0,0}, vv[4] = {0,0,0,0};
        if (n < NN) {
            uchar4 kq = *(const uchar4*)(ks + base + (size_t)n * rstride + d4);
            uchar4 vq = *(const uchar4*)(vs + base + (size_t)n * rstride + d4);
            kv[0] = kq.x ? (short)0x3F80 : 0; kv[1] = kq.y ? (short)0x3F80 : 0;
            kv[2] = kq.z ? (short)0x3F80 : 0; kv[3] = kq.w ? (short)0x3F80 : 0;
            vv[0] = vq.x ? (short)0x3F80 : 0; vv[1] = vq.y ? (short)0x3F80 : 0;
            vv[2] = vq.z ? (short)0x3F80 : 0; vv[3] = vq.w ? (short)0x3F80 : 0;
        }
#pragma unroll
        for (int j = 0; j < 4; ++j) {
            Kt[(d4 + j) * 232 + n] = kv[j];
            Vt[(d4 + j) * 232 + n] = vv[j];
        }
    }
    __syncthreads();

    f32x4 accM[4];
#pragma unroll
    for (int c = 0; c < 4; ++c) accM[c] = (f32x4){0.f,0.f,0.f,0.f};
#pragma unroll
    for (int kc = 0; kc < 7; ++kc) {
        int ko = kc * 32 + quad * 8;
        bf16x8 a = *(const bf16x8*)&Kt[(wave * 16 + r16) * 232 + ko];
#pragma unroll
        for (int c = 0; c < 4; ++c) {
            bf16x8 bfr = *(const bf16x8*)&Vt[(c * 16 + r16) * 232 + ko];
            accM[c] = mfma_bf16(a, bfr, accM[c]);
        }
    }
    __syncthreads();

#pragma unroll
    for (int c = 0; c < 4; ++c)
#pragma unroll
        for (int reg = 0; reg < 4; ++reg) {
            int d1 = wave * 16 + quad * 4 + reg;
            int d2 = c * 16 + r16;
            MT[d2 * 72 + d1] = (short)(__float_as_uint(accM[c][reg]) >> 16);
        }
    for (int i = tid; i < 224 * 16; i += 256) {
        int n = i >> 4;
        int d4 = (i & 15) * 4;
        short qv[4] = {0,0,0,0};
        if (n < NN) {
            uchar4 qq = *(const uchar4*)(qs + base + (size_t)n * rstride + d4);
            qv[0] = qq.x ? (short)0x3F80 : 0; qv[1] = qq.y ? (short)0x3F80 : 0;
            qv[2] = qq.z ? (short)0x3F80 : 0; qv[3] = qq.w ? (short)0x3F80 : 0;
        }
        Qsm[n * 72 + d4 + 0] = qv[0];
        Qsm[n * 72 + d4 + 1] = qv[1];
        Qsm[n * 72 + d4 + 2] = qv[2];
        Qsm[n * 72 + d4 + 3] = qv[3];
    }
    __syncthreads();

    for (int rt = wave; rt < 14; rt += 4) {
        f32x4 acc[4];
#pragma unroll
        for (int c = 0; c < 4; ++c) acc[c] = (f32x4){0.f,0.f,0.f,0.f};
#pragma unroll
        for (int kc = 0; kc < 2; ++kc) {
            int ko = kc * 32 + quad * 8;
            bf16x8 a = *(const bf16x8*)&Qsm[(rt * 16 + r16) * 72 + ko];
#pragma unroll
            for (int c = 0; c < 4; ++c) {
                bf16x8 bfr = *(const bf16x8*)&MT[(c * 16 + r16) * 72 + ko];
                acc[c] = mfma_bf16(a, bfr, acc[c]);
            }
        }
#pragma unroll
        for (int c = 0; c < 4; ++c)
#pragma unroll
            for (int reg = 0; reg < 4; ++reg) {
                int n = rt * 16 + quad * 4 + reg;
                if (n < NN) {
                    float val = acc[c][reg] * 0.125f;      // exact
                    ushort_t hv = f2bf(val);
                    float lo = val - bf2f(hv);             // exact residual
                    size_t off = base + (size_t)n * rstride + c * 16 + r16;
                    Ah[off] = hv;
                    Al[off] = f2bf(lo);
                }
            }
    }
}

// ---------------------------------------------------------------------------
extern "C" void kernel_launch(void* const* d_in, const int* in_sizes, int n_in,
                              void* d_out, int out_size, void* d_ws, size_t ws_size,
                              hipStream_t stream)
{
    const float* x      = (const float*)d_in[0];
    const float* ln1_g  = (const float*)d_in[1];
    const float* ln1_b  = (const float*)d_in[2];
    const float* wq     = (const float*)d_in[3];
    const float* wk     = (const float*)d_in[4];
    const float* wv     = (const float*)d_in[5];
    const float* proj_w = (const float*)d_in[6];
    const float* proj_b = (const float*)d_in[7];
    const float* ln2_g  = (const float*)d_in[8];
    const float* ln2_b  = (const float*)d_in[9];
    const float* fc1_w  = (const float*)d_in[10];
    const float* fc1_b  = (const float*)d_in[11];
    const float* fc2_w  = (const float*)d_in[12];
    const float* fc2_b  = (const float*)d_in[13];
    float* outp = (float*)d_out;

    // workspace layout (bytes), peak ~171 MB
    const size_t P1 = (size_t)RR * DD;                 // 12,910,592 elements
    char* wsb = (char*)d_ws;
    ushort_t* A0  = (ushort_t*)(wsb + 0);              // LN splits (2 bf16 planes)
    ushort_t* A1  = (ushort_t*)(wsb + P1 * 2);
    u8*       qs  = (u8*)(wsb + P1 * 4);
    u8*       ksp = (u8*)(wsb + P1 * 5);
    u8*       vsp = (u8*)(wsb + P1 * 6);
    u8*       sp  = (u8*)(wsb + P1 * 7);
    ushort_t* Ah  = (ushort_t*)(wsb + P1 * 8);
    ushort_t* Al  = (ushort_t*)(wsb + P1 * 10);
    u8*       hsp = (u8*)(wsb + P1 * 8);               // RR x 2048 u8, aliases Ah/Al
    char*     wpl = wsb + P1 * 12;                     // weight split planes
    ushort_t* wq0 = (ushort_t*)(wpl);                  // 6 x DD*DD bf16
    ushort_t* wq1 = wq0 + (size_t)DD * DD;
    ushort_t* wk0 = wq1 + (size_t)DD * DD;
    ushort_t* wk1 = wk0 + (size_t)DD * DD;
    ushort_t* wv0 = wk1 + (size_t)DD * DD;
    ushort_t* wv1 = wv0 + (size_t)DD * DD;
    ushort_t* wp0 = wv1 + (size_t)DD * DD;             // 3 x DD*DD
    ushort_t* wp1 = wp0 + (size_t)DD * DD;
    ushort_t* wp2 = wp1 + (size_t)DD * DD;
    ushort_t* f10 = wp2 + (size_t)DD * DD;             // 2 x DH*DD
    ushort_t* f11 = f10 + (size_t)DH * DD;
    ushort_t* f20 = f11 + (size_t)DH * DD;             // 2 x DD*DH
    ushort_t* f21 = f20 + (size_t)DD * DH;
    uint32_t* cnt  = (uint32_t*)((char*)(f21 + (size_t)DD * DH) + 0);
    uint32_t* list = (uint32_t*)((char*)cnt + 256);

    zero_kernel<<<1, 64, 0, stream>>>(cnt);

    // weight pre-splits
    wsplit2<<<(DD*DD+255)/256, 256, 0, stream>>>(wq, wq0, wq1, DD*DD);
    wsplit2<<<(DD*DD+255)/256, 256, 0, stream>>>(wk, wk0, wk1, DD*DD);
    wsplit2<<<(DD*DD+255)/256, 256, 0, stream>>>(wv, wv0, wv1, DD*DD);
    wsplit3<<<(DD*DD+255)/256, 256, 0, stream>>>(proj_w, wp0, wp1, wp2, DD*DD);
    wsplit2<<<(DH*DD+255)/256, 256, 0, stream>>>(fc1_w, f10, f11, DH*DD);
    wsplit2<<<(DD*DH+255)/256, 256, 0, stream>>>(fc2_w, f20, f21, DD*DH);

    // LN1 -> splits (r'-layout)
    ln_split<0><<<RR, 64, 0, stream>>>(x, nullptr, ln1_g, ln1_b, A0, A1);

    // q/k/v GEMMs (split-bf16, fused LIF) + fp64 refine
    dim3 g8(4, RR/128), g32(DH/128, RR/128);
    gemm128<2,2,0,0><<<g8, 256, 0, stream>>>(A0, A1, nullptr, wq0, wq1, nullptr,
        nullptr, DD, DD, 3e-4f, qs, nullptr, nullptr, nullptr, cnt+0, list+0*LCAP);
    gemm128<2,2,0,0><<<g8, 256, 0, stream>>>(A0, A1, nullptr, wk0, wk1, nullptr,
        nullptr, DD, DD, 3e-4f, ksp, nullptr, nullptr, nullptr, cnt+1, list+1*LCAP);
    gemm128<2,2,0,0><<<g8, 256, 0, stream>>>(A0, A1, nullptr, wv0, wv1, nullptr,
        nullptr, DD, DD, 3e-4f, vsp, nullptr, nullptr, nullptr, cnt+2, list+2*LCAP);
    refine_spike<0><<<128, 256, 0, stream>>>(cnt+0, list+0*LCAP, x, nullptr,
        nullptr, nullptr, ln1_g, ln1_b, wq, nullptr, DD, qs);
    refine_spike<0><<<128, 256, 0, stream>>>(cnt+1, list+1*LCAP, x, nullptr,
        nullptr, nullptr, ln1_g, ln1_b, wk, nullptr, DD, ksp);
    refine_spike<0><<<128, 256, 0, stream>>>(cnt+2, list+2*LCAP, x, nullptr,
        nullptr, nullptr, ln1_g, ln1_b, wv, nullptr, DD, vsp);

    // linear attention (exact), bf16 hi/lo output
    attn_kernel<<<T_STEPS * BB * 8, 256, 0, stream>>>(qs, ksp, vsp, Ah, Al);

    // proj GEMM (NSB=3: large |p|) + refine -> sp
    gemm128<2,3,0,0><<<g8, 256, 0, stream>>>(Ah, Al, nullptr, wp0, wp1, wp2,
        proj_b, DD, DD, 1e-3f, sp, nullptr, nullptr, nullptr, cnt+3, list+3*LCAP);
    refine_spike<1><<<128, 256, 0, stream>>>(cnt+3, list+3*LCAP, nullptr, nullptr,
        Ah, Al, nullptr, nullptr, proj_w, proj_b, DD, sp);

    // LN2 of (x + sp) -> splits
    ln_split<1><<<RR, 64, 0, stream>>>(x, sp, ln2_g, ln2_b, A0, A1);

    // fc1 GEMM + refine -> h spikes (u8)
    gemm128<2,2,0,0><<<g32, 256, 0, stream>>>(A0, A1, nullptr, f10, f11, nullptr,
        fc1_b, DH, DD, 3e-4f, hsp, nullptr, nullptr, nullptr, cnt+4, list+4*LCAP);
    refine_spike<0><<<128, 256, 0, stream>>>(cnt+4, list+4*LCAP, x, sp,
        nullptr, nullptr, ln2_g, ln2_b, fc1_w, fc1_b, DH, hsp);

    // fc2 GEMM (binary A) + LIF + residuals -> fp32 out, then refine
    gemm128<1,2,1,2><<<g8, 256, 0, stream>>>(nullptr, nullptr, hsp, f20, f21, nullptr,
        fc2_b, DD, DH, 3e-4f, nullptr, outp, x, sp, cnt+5, list+5*LCAP);
    refine_out<<<128, 256, 0, stream>>>(cnt+5, list+5*LCAP, hsp, fc2_w, fc2_b,
        x, sp, outp);
}

// Round 5
// 873.079 us; speedup vs baseline: 3.7779x; 1.2300x over previous
//
#include <hip/hip_runtime.h>
#include <stdint.h>
#include <math.h>

#define T_STEPS 4
#define BB 32
#define NN 197
#define DD 512
#define DH 2048
#define RR (T_STEPS*BB*NN)          // 25216 rows (r'-layout: bn*4+t)
#define RPT (BB*NN)                 // 6304
#define LCAP 131072u

typedef unsigned short ushort_t;
typedef unsigned char u8;
typedef __attribute__((ext_vector_type(8))) short bf16x8;
typedef __attribute__((ext_vector_type(4))) float f32x4;

__device__ __forceinline__ float bf2f(ushort_t h) {
    return __uint_as_float(((uint32_t)h) << 16);
}
__device__ __forceinline__ ushort_t f2bf(float f) {
    uint32_t u = __float_as_uint(f);
    uint32_t r = (u + 0x7fffu + ((u >> 16) & 1u)) >> 16;
    return (ushort_t)r;
}
__device__ __forceinline__ f32x4 mfma_bf16(bf16x8 a, bf16x8 b, f32x4 c) {
    return __builtin_amdgcn_mfma_f32_16x16x32_bf16(a, b, c, 0, 0, 0);
}
__device__ __forceinline__ void gll16(const void* gptr, void* lptr) {
    __builtin_amdgcn_global_load_lds(
        (const __attribute__((address_space(1))) uint32_t*)(uintptr_t)gptr,
        (__attribute__((address_space(3))) uint32_t*)(uintptr_t)lptr,
        16, 0, 0);
}
__device__ __forceinline__ double wred(double x) {
#pragma unroll
    for (int o = 32; o; o >>= 1) x += __shfl_xor(x, o, 64);
    return x;
}
// bank-conflict-breaking column swizzle: permute aligned 8-blocks within each
// 64-column group by row&7.  Applied at plane write; un-xored at ds_read.
__device__ __forceinline__ int swzk(int k, int row) {
    return (k & ~63) | ((k & 63) ^ ((row & 7) << 3));
}

__global__ void zero_kernel(uint32_t* p) {
    if (threadIdx.x < 8) p[threadIdx.x] = 0;
}

// ---------------------------------------------------------------------------
// weight pre-split fp32 -> bf16 planes (exact), stored column-swizzled
// ---------------------------------------------------------------------------
__global__ __launch_bounds__(256) void wsplit2(const float* __restrict__ w,
    ushort_t* __restrict__ w0, ushort_t* __restrict__ w1, int n, int K) {
    int i = blockIdx.x * 256 + threadIdx.x;
    if (i >= n) return;
    int row = i / K;
    int so = (i & ~63) | ((i & 63) ^ ((row & 7) << 3));
    float v = w[i];
    ushort_t h0 = f2bf(v);
    w0[so] = h0;
    w1[so] = f2bf(v - bf2f(h0));
}
__global__ __launch_bounds__(256) void wsplit3(const float* __restrict__ w,
    ushort_t* __restrict__ w0, ushort_t* __restrict__ w1,
    ushort_t* __restrict__ w2, int n, int K) {
    int i = blockIdx.x * 256 + threadIdx.x;
    if (i >= n) return;
    int row = i / K;
    int so = (i & ~63) | ((i & 63) ^ ((row & 7) << 3));
    float v = w[i];
    ushort_t h0 = f2bf(v);  float r1 = v - bf2f(h0);
    ushort_t h1 = f2bf(r1); float r2 = r1 - bf2f(h1);
    w0[so] = h0; w1[so] = h1; w2[so] = f2bf(r2);
}

// ---------------------------------------------------------------------------
// LayerNorm (fp64) -> 2-way bf16 split, r'-layout rows, swizzled columns.
// 4 rows per block (one wave each).  HAS_SP: add u8 spike plane (r'-layout).
// ---------------------------------------------------------------------------
template<int HAS_SP>
__global__ __launch_bounds__(256) void ln_split(
    const float* __restrict__ xin, const u8* __restrict__ spp,
    const float* __restrict__ gw, const float* __restrict__ bw,
    ushort_t* __restrict__ y0, ushort_t* __restrict__ y1)
{
    int wave = threadIdx.x >> 6, lane = threadIdx.x & 63;
    int id = blockIdx.x * 4 + wave;      // t-major row id
    int t = id / RPT, rem = id % RPT;
    size_t rp = (size_t)rem * 4 + t;

    const float* xp = xin + (size_t)id * DD + (size_t)lane * 8;
    float4 a = *(const float4*)xp;
    float4 bq = *(const float4*)(xp + 4);
    double v[8] = {a.x, a.y, a.z, a.w, bq.x, bq.y, bq.z, bq.w};
    if (HAS_SP) {
        const u8* sp8 = spp + rp * DD + (size_t)lane * 8;
#pragma unroll
        for (int i = 0; i < 8; ++i) v[i] += (double)sp8[i];
    }

    double s = 0.0;
#pragma unroll
    for (int i = 0; i < 8; ++i) s += v[i];
    s = wred(s);
    double m = s * (1.0 / 512.0);
    double d[8], ss = 0.0;
#pragma unroll
    for (int i = 0; i < 8; ++i) { d[i] = v[i] - m; ss += d[i] * d[i]; }
    ss = wred(ss);
    double rstd = 1.0 / sqrt(ss * (1.0 / 512.0) + 1e-5);

    float4 g1 = *(const float4*)(gw + lane * 8);
    float4 g2 = *(const float4*)(gw + lane * 8 + 4);
    float4 b1 = *(const float4*)(bw + lane * 8);
    float4 b2 = *(const float4*)(bw + lane * 8 + 4);
    double gg[8] = {g1.x, g1.y, g1.z, g1.w, g2.x, g2.y, g2.z, g2.w};
    double bb[8] = {b1.x, b1.y, b1.z, b1.w, b2.x, b2.y, b2.z, b2.w};

    bf16x8 o0, o1;
#pragma unroll
    for (int i = 0; i < 8; ++i) {
        float y = (float)(d[i] * rstd * gg[i] + bb[i]);
        ushort_t h0 = f2bf(y);
        o0[i] = (short)h0;
        o1[i] = (short)f2bf(y - bf2f(h0));
    }
    size_t off = rp * DD + swzk(lane * 8, (int)rp);
    *(bf16x8*)(y0 + off) = o0;
    *(bf16x8*)(y1 + off) = o1;
}

// ---------------------------------------------------------------------------
// Split-bf16 GEMM, 128x128 tile, BK=64, 4 waves, global_load_lds staging,
// swizzled plane layout (conflict-free ds_read), fused LIF + suspect list.
// MFMA set: a0b0,a0b1[,a0b2],a1b0 (+a1b1 only when NSB==3 — proj precision).
// ---------------------------------------------------------------------------
template<int NSA, int NSB, int AU8, int EPI, int NMAT>
__global__ __launch_bounds__(256) void gemm128(
    const ushort_t* __restrict__ A0p, const ushort_t* __restrict__ A1p,
    const u8* __restrict__ A8p,
    const ushort_t* __restrict__ B0p, const ushort_t* __restrict__ B1p,
    const ushort_t* __restrict__ B2p,
    const float* __restrict__ biasp, int N, int K, float delta,
    u8* __restrict__ s0, u8* __restrict__ s1, u8* __restrict__ s2,
    float* __restrict__ fout,
    const float* __restrict__ xres, const u8* __restrict__ spres,
    uint32_t* __restrict__ cnt, uint32_t* __restrict__ list)
{
    __shared__ short lds[(NSA + NSB) * 8192];

    int tid = threadIdx.x, lane = tid & 63, wave = tid >> 6;
    int quad = lane >> 4, r16 = lane & 15;
    int n0 = blockIdx.x * 128, m0 = blockIdx.y * 128;
    int wm = (wave & 1) * 64, wn = (wave >> 1) * 64;

    const ushort_t* Aps[2] = {A0p, A1p};
    const ushort_t* Bps[3] = {B0p, B1p, B2p};

    f32x4 acc[4][4];
#pragma unroll
    for (int rt = 0; rt < 4; ++rt)
#pragma unroll
        for (int ct = 0; ct < 4; ++ct) acc[rt][ct] = (f32x4){0.f,0.f,0.f,0.f};

    for (int k0 = 0; k0 < K; k0 += 64) {
        __syncthreads();
        if (AU8) {
#pragma unroll
            for (int i = 0; i < 2; ++i) {
                int g = i * 256 + tid;
                int row = g >> 2, kc = (g & 3) * 16;
                int sw = (row & 7) << 3;
                const u8* src = A8p + (size_t)(m0 + row) * K + k0 + kc;
                uint4 raw = *(const uint4*)src;
                uint32_t wsr[4] = {raw.x, raw.y, raw.z, raw.w};
                short tmp[16];
#pragma unroll
                for (int j = 0; j < 4; ++j)
#pragma unroll
                    for (int bp = 0; bp < 4; ++bp)
                        tmp[j*4+bp] = ((wsr[j] >> (8*bp)) & 0xFFu) ? (short)0x3F80 : (short)0;
                *(bf16x8*)&lds[row * 64 + (kc ^ sw)]       = *(bf16x8*)&tmp[0];
                *(bf16x8*)&lds[row * 64 + ((kc + 8) ^ sw)] = *(bf16x8*)&tmp[8];
            }
        } else {
#pragma unroll
            for (int p = 0; p < NSA; ++p)
#pragma unroll
                for (int i = 0; i < 4; ++i) {
                    int c = i * 4 + wave;
                    int row = c * 8 + (lane >> 3);
                    int kc = (lane & 7) * 8;
                    gll16(Aps[p] + (size_t)(m0 + row) * K + k0 + kc,
                          &lds[p * 8192 + c * 512]);
                }
        }
#pragma unroll
        for (int q = 0; q < NSB; ++q)
#pragma unroll
            for (int i = 0; i < 4; ++i) {
                int c = i * 4 + wave;
                int row = c * 8 + (lane >> 3);
                int kc = (lane & 7) * 8;
                gll16(Bps[q] + (size_t)(n0 + row) * K + k0 + kc,
                      &lds[(NSA + q) * 8192 + c * 512]);
            }
        __syncthreads();

#pragma unroll
        for (int sub = 0; sub < 2; ++sub) {
            const int ko = sub * 32 + quad * 8;
            bf16x8 af[4][2], bfv[4][3];
#pragma unroll
            for (int rt = 0; rt < 4; ++rt) {
                int r = wm + rt * 16 + r16;
#pragma unroll
                for (int p = 0; p < NSA; ++p)
                    af[rt][p] = *(const bf16x8*)&lds[p * 8192 + r * 64 + (ko ^ ((r & 7) << 3))];
            }
#pragma unroll
            for (int ct = 0; ct < 4; ++ct) {
                int r = wn + ct * 16 + r16;
#pragma unroll
                for (int q = 0; q < NSB; ++q)
                    bfv[ct][q] = *(const bf16x8*)&lds[(NSA + q) * 8192 + r * 64 + (ko ^ ((r & 7) << 3))];
            }
#pragma unroll
            for (int rt = 0; rt < 4; ++rt)
#pragma unroll
                for (int ct = 0; ct < 4; ++ct) {
                    f32x4 a = acc[rt][ct];
                    if (NSB == 3)             a = mfma_bf16(af[rt][0], bfv[ct][2], a);
                    if (NSA == 2 && NSB == 3) a = mfma_bf16(af[rt][1], bfv[ct][1], a);
                    if (NSA == 2)             a = mfma_bf16(af[rt][1], bfv[ct][0], a);
                    a = mfma_bf16(af[rt][0], bfv[ct][1], a);
                    a = mfma_bf16(af[rt][0], bfv[ct][0], a);
                    acc[rt][ct] = a;
                }
        }
    }

    // epilogue: each lane owns T=4 steps of 16 neurons (r'-layout rows)
#pragma unroll
    for (int rt = 0; rt < 4; ++rt) {
        int rbase = m0 + wm + rt * 16 + quad * 4;
        int bn = rbase >> 2;
#pragma unroll
        for (int ct = 0; ct < 4; ++ct) {
            int col = n0 + wn + ct * 16 + r16;
            float bv = biasp ? biasp[col] : 0.0f;
            float v = 0.f;
            bool nearf = false;
#pragma unroll
            for (int t = 0; t < 4; ++t) {
                float p = acc[rt][ct][t] + bv;
                v = v + (p - v) * 0.5f;
                nearf |= (fabsf(v - 1.0f) < delta);
                int s = (v >= 1.0f);
                if (EPI == 0) {
                    if (NMAT == 3) {
                        int mat = col >> 9, cc = col & 511;
                        u8* sp = (mat == 0) ? s0 : ((mat == 1) ? s1 : s2);
                        sp[(size_t)(rbase + t) * 512 + cc] = (u8)s;
                    } else {
                        s0[(size_t)(rbase + t) * N + col] = (u8)s;
                    }
                } else {
                    int b = bn / NN, n = bn % NN;
                    size_t oi = (((size_t)t * BB + b) * NN + n) * DD + col;
                    fout[oi] = (float)((double)xres[oi]
                             + (double)spres[(size_t)(rbase + t) * DD + col]
                             + (double)s);
                }
                if (s) v = 0.f;
            }
            if (nearf) {
                uint32_t idx = atomicAdd(cnt, 1u);
                if (idx < LCAP) list[idx] = (uint32_t)bn * (uint32_t)N + (uint32_t)col;
            }
        }
    }
}

// ---------------------------------------------------------------------------
// fp64 refinement helpers
// ---------------------------------------------------------------------------
__device__ __forceinline__ void ln_recompute_row(
    const float* __restrict__ xr, const u8* __restrict__ sr, int lane,
    const float* __restrict__ lng, const float* __restrict__ lnb, double* yv)
{
    double xv[8], s = 0.0;
#pragma unroll
    for (int j = 0; j < 8; ++j) {
        int k = j * 64 + lane;
        double val = (double)xr[k];
        if (sr) val += (double)sr[k];
        xv[j] = val; s += val;
    }
    s = wred(s);
    double m = s * (1.0 / 512.0), ss = 0.0;
#pragma unroll
    for (int j = 0; j < 8; ++j) { double d = xv[j] - m; ss += d * d; }
    ss = wred(ss);
    double rstd = 1.0 / sqrt(ss * (1.0 / 512.0) + 1e-5);
#pragma unroll
    for (int j = 0; j < 8; ++j) {
        int k = j * 64 + lane;
        yv[j] = (xv[j] - m) * rstd * (double)lng[k] + (double)lnb[k];
    }
}

// fused-qkv refinement (N=1536 id encoding; no bias)
__global__ __launch_bounds__(256) void refine_qkv(
    const uint32_t* __restrict__ cnt, const uint32_t* __restrict__ list,
    const float* __restrict__ x,
    const float* __restrict__ lng, const float* __restrict__ lnb,
    const float* __restrict__ wq, const float* __restrict__ wk,
    const float* __restrict__ wv,
    u8* __restrict__ qs, u8* __restrict__ ks, u8* __restrict__ vs)
{
    int lane = threadIdx.x & 63;
    int wid = (blockIdx.x * 256 + threadIdx.x) >> 6;
    int nw = (gridDim.x * 256) >> 6;
    uint32_t nsus = *cnt; if (nsus > LCAP) nsus = LCAP;
    for (uint32_t i = wid; i < nsus; i += nw) {
        uint32_t id = list[i];
        int col1536 = (int)(id % 1536u);
        int bn = (int)(id / 1536u);
        int mat = col1536 >> 9, col = col1536 & 511;
        const float* W = (mat == 0) ? wq : ((mat == 1) ? wk : wv);
        u8* spout = (mat == 0) ? qs : ((mat == 1) ? ks : vs);
        double p[4];
#pragma unroll
        for (int t = 0; t < 4; ++t) {
            const float* xr = x + ((size_t)t * RPT + bn) * DD;
            double yv[8];
            ln_recompute_row(xr, nullptr, lane, lng, lnb, yv);
            double dot = 0.0;
#pragma unroll
            for (int j = 0; j < 8; ++j)
                dot += yv[j] * (double)W[(size_t)col * DD + j * 64 + lane];
            p[t] = wred(dot);
        }
        if (lane == 0) {
            double v = 0.0;
#pragma unroll
            for (int t = 0; t < 4; ++t) {
                v = v + (p[t] - v) * 0.5;
                int s = (v >= 1.0);
                spout[(size_t)(bn * 4 + t) * 512 + col] = (u8)s;
                if (s) v = 0.0;
            }
        }
    }
}

// generic LN-input refinement (fc1)
__global__ __launch_bounds__(256) void refine_ln(
    const uint32_t* __restrict__ cnt, const uint32_t* __restrict__ list,
    const float* __restrict__ x, const u8* __restrict__ spres,
    const float* __restrict__ lng, const float* __restrict__ lnb,
    const float* __restrict__ W, const float* __restrict__ biasp,
    int N, u8* __restrict__ spout)
{
    int lane = threadIdx.x & 63;
    int wid = (blockIdx.x * 256 + threadIdx.x) >> 6;
    int nw = (gridDim.x * 256) >> 6;
    uint32_t nsus = *cnt; if (nsus > LCAP) nsus = LCAP;
    for (uint32_t i = wid; i < nsus; i += nw) {
        uint32_t id = list[i];
        int col = (int)(id % (uint32_t)N);
        int bn  = (int)(id / (uint32_t)N);
        double p[4];
#pragma unroll
        for (int t = 0; t < 4; ++t) {
            size_t rp = (size_t)bn * 4 + t;
            const float* xr = x + ((size_t)t * RPT + bn) * DD;
            double yv[8];
            ln_recompute_row(xr, spres + rp * DD, lane, lng, lnb, yv);
            double dot = 0.0;
#pragma unroll
            for (int j = 0; j < 8; ++j)
                dot += yv[j] * (double)W[(size_t)col * DD + j * 64 + lane];
            dot = wred(dot);
            p[t] = dot + (double)biasp[col];
        }
        if (lane == 0) {
            double v = 0.0;
#pragma unroll
            for (int t = 0; t < 4; ++t) {
                v = v + (p[t] - v) * 0.5;
                int s = (v >= 1.0);
                spout[(size_t)(bn * 4 + t) * N + col] = (u8)s;
                if (s) v = 0.0;
            }
        }
    }
}

// proj refinement: A = swizzled exact bf16 pair Ah/Al
__global__ __launch_bounds__(256) void refine_proj(
    const uint32_t* __restrict__ cnt, const uint32_t* __restrict__ list,
    const ushort_t* __restrict__ Ah, const ushort_t* __restrict__ Al,
    const float* __restrict__ W, const float* __restrict__ biasp,
    u8* __restrict__ spout)
{
    int lane = threadIdx.x & 63;
    int wid = (blockIdx.x * 256 + threadIdx.x) >> 6;
    int nw = (gridDim.x * 256) >> 6;
    uint32_t nsus = *cnt; if (nsus > LCAP) nsus = LCAP;
    for (uint32_t i = wid; i < nsus; i += nw) {
        uint32_t id = list[i];
        int col = (int)(id % (uint32_t)DD);
        int bn  = (int)(id / (uint32_t)DD);
        double p[4];
#pragma unroll
        for (int t = 0; t < 4; ++t) {
            size_t rp = (size_t)bn * 4 + t;
            int sw = ((int)rp & 7) << 3;
            double dot = 0.0;
#pragma unroll
            for (int j = 0; j < 8; ++j) {
                size_t addr = rp * DD + j * 64 + (lane ^ sw);
                double a = (double)bf2f(Ah[addr]) + (double)bf2f(Al[addr]);
                dot += a * (double)W[(size_t)col * DD + j * 64 + lane];
            }
            dot = wred(dot);
            p[t] = dot + (double)biasp[col];
        }
        if (lane == 0) {
            double v = 0.0;
#pragma unroll
            for (int t = 0; t < 4; ++t) {
                v = v + (p[t] - v) * 0.5;
                int s = (v >= 1.0);
                spout[(size_t)(bn * 4 + t) * DD + col] = (u8)s;
                if (s) v = 0.0;
            }
        }
    }
}

// fc2 refinement: A = u8 h (K=2048), rewrites fp32 outputs with residuals
__global__ __launch_bounds__(256) void refine_out(
    const uint32_t* __restrict__ cnt, const uint32_t* __restrict__ list,
    const u8* __restrict__ hsp, const float* __restrict__ W,
    const float* __restrict__ biasp,
    const float* __restrict__ xin, const u8* __restrict__ spres,
    float* __restrict__ fout)
{
    int lane = threadIdx.x & 63;
    int wid = (blockIdx.x * 256 + threadIdx.x) >> 6;
    int nw = (gridDim.x * 256) >> 6;
    uint32_t nsus = *cnt; if (nsus > LCAP) nsus = LCAP;
    for (uint32_t i = wid; i < nsus; i += nw) {
        uint32_t id = list[i];
        int col = (int)(id % (uint32_t)DD);
        int bn  = (int)(id / (uint32_t)DD);
        double p[4];
#pragma unroll
        for (int t = 0; t < 4; ++t) {
            size_t rp = (size_t)bn * 4 + t;
            double dot = 0.0;
#pragma unroll
            for (int j = 0; j < 32; ++j) {
                int k = j * 64 + lane;
                dot += (double)hsp[rp * DH + k] * (double)W[(size_t)col * DH + k];
            }
            dot = wred(dot);
            p[t] = dot + (double)biasp[col];
        }
        if (lane == 0) {
            int b = bn / NN, n = bn % NN;
            double v = 0.0;
#pragma unroll
            for (int t = 0; t < 4; ++t) {
                v = v + (p[t] - v) * 0.5;
                int s = (v >= 1.0);
                size_t oi = (((size_t)t * BB + b) * NN + n) * DD + col;
                fout[oi] = (float)((double)xin[oi]
                         + (double)spres[(size_t)(bn * 4 + t) * DD + col]
                         + (double)s);
                if (s) v = 0.0;
            }
        }
    }
}

// ---------------------------------------------------------------------------
// Attention per (t,b,h): out = Q (K^T V) / 8 — binary u8 spikes, integer-
// exact.  Output = exact bf16 hi/lo pair, SWIZZLED columns (gemm plane).
// ---------------------------------------------------------------------------
__global__ __launch_bounds__(256) void attn_kernel(
    const u8* __restrict__ qs, const u8* __restrict__ ks,
    const u8* __restrict__ vs,
    ushort_t* __restrict__ Ah, ushort_t* __restrict__ Al)
{
    __shared__ __align__(16) short sm[29696];
    short* Kt = sm;              // 64 x 232
    short* Vt = sm + 14848;      // 64 x 232
    short* MT = sm + 25088;      // 64 x 72
    short* Qsm = sm;             // 224 x 72

    int bid = blockIdx.x;
    int t = bid >> 8;
    int b = (bid >> 3) & 31;
    int h = bid & 7;
    size_t base = ((size_t)(b * NN) * 4 + t) * DD + (size_t)h * 64;
    const size_t rstride = (size_t)4 * DD;

    int tid = threadIdx.x;
    int lane = tid & 63, wave = tid >> 6;
    int quad = lane >> 4, r16 = lane & 15;

    for (int i = tid; i < 224 * 16; i += 256) {
        int n = i >> 4;
        int d4 = (i & 15) * 4;
        short kv[4] = {0,0,0,0}, vv[4] = {0,0,0,0};
        if (n < NN) {
            uchar4 kq = *(const uchar4*)(ks + base + (size_t)n * rstride + d4);
            uchar4 vq = *(const uchar4*)(vs + base + (size_t)n * rstride + d4);
            kv[0] = kq.x ? (short)0x3F80 : 0; kv[1] = kq.y ? (short)0x3F80 : 0;
            kv[2] = kq.z ? (short)0x3F80 : 0; kv[3] = kq.w ? (short)0x3F80 : 0;
            vv[0] = vq.x ? (short)0x3F80 : 0; vv[1] = vq.y ? (short)0x3F80 : 0;
            vv[2] = vq.z ? (short)0x3F80 : 0; vv[3] = vq.w ? (short)0x3F80 : 0;
        }
#pragma unroll
        for (int j = 0; j < 4; ++j) {
            Kt[(d4 + j) * 232 + n] = kv[j];
            Vt[(d4 + j) * 232 + n] = vv[j];
        }
    }
    __syncthreads();

    f32x4 accM[4];
#pragma unroll
    for (int c = 0; c < 4; ++c) accM[c] = (f32x4){0.f,0.f,0.f,0.f};
#pragma unroll
    for (int kc = 0; kc < 7; ++kc) {
        int ko = kc * 32 + quad * 8;
        bf16x8 a = *(const bf16x8*)&Kt[(wave * 16 + r16) * 232 + ko];
#pragma unroll
        for (int c = 0; c < 4; ++c) {
            bf16x8 bfr = *(const bf16x8*)&Vt[(c * 16 + r16) * 232 + ko];
            accM[c] = mfma_bf16(a, bfr, accM[c]);
        }
    }
    __syncthreads();

#pragma unroll
    for (int c = 0; c < 4; ++c)
#pragma unroll
        for (int reg = 0; reg < 4; ++reg) {
            int d1 = wave * 16 + quad * 4 + reg;
            int d2 = c * 16 + r16;
            MT[d2 * 72 + d1] = (short)(__float_as_uint(accM[c][reg]) >> 16);
        }
    for (int i = tid; i < 224 * 16; i += 256) {
        int n = i >> 4;
        int d4 = (i & 15) * 4;
        short qv[4] = {0,0,0,0};
        if (n < NN) {
            uchar4 qq = *(const uchar4*)(qs + base + (size_t)n * rstride + d4);
            qv[0] = qq.x ? (short)0x3F80 : 0; qv[1] = qq.y ? (short)0x3F80 : 0;
            qv[2] = qq.z ? (short)0x3F80 : 0; qv[3] = qq.w ? (short)0x3F80 : 0;
        }
        Qsm[n * 72 + d4 + 0] = qv[0];
        Qsm[n * 72 + d4 + 1] = qv[1];
        Qsm[n * 72 + d4 + 2] = qv[2];
        Qsm[n * 72 + d4 + 3] = qv[3];
    }
    __syncthreads();

    for (int rt = wave; rt < 14; rt += 4) {
        f32x4 acc[4];
#pragma unroll
        for (int c = 0; c < 4; ++c) acc[c] = (f32x4){0.f,0.f,0.f,0.f};
#pragma unroll
        for (int kc = 0; kc < 2; ++kc) {
            int ko = kc * 32 + quad * 8;
            bf16x8 a = *(const bf16x8*)&Qsm[(rt * 16 + r16) * 72 + ko];
#pragma unroll
            for (int c = 0; c < 4; ++c) {
                bf16x8 bfr = *(const bf16x8*)&MT[(c * 16 + r16) * 72 + ko];
                acc[c] = mfma_bf16(a, bfr, acc[c]);
            }
        }
#pragma unroll
        for (int c = 0; c < 4; ++c)
#pragma unroll
            for (int reg = 0; reg < 4; ++reg) {
                int n = rt * 16 + quad * 4 + reg;
                if (n < NN) {
                    float val = acc[c][reg] * 0.125f;      // exact
                    ushort_t hv = f2bf(val);
                    float lo = val - bf2f(hv);             // exact residual
                    // swizzle: row rp=(b*197+n)*4+t -> rp&7 = ((b+n)&1)*4+t
                    int sw = ((((b + n) & 1) << 2) | t) << 3;
                    size_t off = base + (size_t)n * rstride + ((c * 16 + r16) ^ sw);
                    Ah[off] = hv;
                    Al[off] = f2bf(lo);
                }
            }
    }
}

// ---------------------------------------------------------------------------
extern "C" void kernel_launch(void* const* d_in, const int* in_sizes, int n_in,
                              void* d_out, int out_size, void* d_ws, size_t ws_size,
                              hipStream_t stream)
{
    const float* x      = (const float*)d_in[0];
    const float* ln1_g  = (const float*)d_in[1];
    const float* ln1_b  = (const float*)d_in[2];
    const float* wq     = (const float*)d_in[3];
    const float* wk     = (const float*)d_in[4];
    const float* wv     = (const float*)d_in[5];
    const float* proj_w = (const float*)d_in[6];
    const float* proj_b = (const float*)d_in[7];
    const float* ln2_g  = (const float*)d_in[8];
    const float* ln2_b  = (const float*)d_in[9];
    const float* fc1_w  = (const float*)d_in[10];
    const float* fc1_b  = (const float*)d_in[11];
    const float* fc2_w  = (const float*)d_in[12];
    const float* fc2_b  = (const float*)d_in[13];
    float* outp = (float*)d_out;

    const size_t P1 = (size_t)RR * DD;                 // 12,910,592 elements
    char* wsb = (char*)d_ws;
    size_t off = 0;
    ushort_t* A0  = (ushort_t*)(wsb + off); off += P1 * 2;
    ushort_t* A1  = (ushort_t*)(wsb + off); off += P1 * 2;
    u8*       qs  = (u8*)(wsb + off); off += P1;
    u8*       ksp = (u8*)(wsb + off); off += P1;
    u8*       vsp = (u8*)(wsb + off); off += P1;
    u8*       sp  = (u8*)(wsb + off); off += P1;
    ushort_t* Ah  = (ushort_t*)(wsb + off); off += P1 * 2;
    ushort_t* Al  = (ushort_t*)(wsb + off); off += P1 * 2;
    u8*       hsp = (u8*)Ah;                           // RR x 2048 u8, aliases Ah+Al
    ushort_t* wqkv0 = (ushort_t*)(wsb + off); off += (size_t)3 * DD * DD * 2;
    ushort_t* wqkv1 = (ushort_t*)(wsb + off); off += (size_t)3 * DD * DD * 2;
    ushort_t* wp0 = (ushort_t*)(wsb + off); off += (size_t)DD * DD * 2;
    ushort_t* wp1 = (ushort_t*)(wsb + off); off += (size_t)DD * DD * 2;
    ushort_t* wp2 = (ushort_t*)(wsb + off); off += (size_t)DD * DD * 2;
    ushort_t* f10 = (ushort_t*)(wsb + off); off += (size_t)DH * DD * 2;
    ushort_t* f11 = (ushort_t*)(wsb + off); off += (size_t)DH * DD * 2;
    ushort_t* f20 = (ushort_t*)(wsb + off); off += (size_t)DD * DH * 2;
    ushort_t* f21 = (ushort_t*)(wsb + off); off += (size_t)DD * DH * 2;
    uint32_t* cnt  = (uint32_t*)(wsb + off); off += 256;
    uint32_t* list = (uint32_t*)(wsb + off);

    zero_kernel<<<1, 64, 0, stream>>>(cnt);

    // weight pre-splits (swizzled)
    wsplit2<<<(DD*DD+255)/256, 256, 0, stream>>>(wq, wqkv0, wqkv1, DD*DD, DD);
    wsplit2<<<(DD*DD+255)/256, 256, 0, stream>>>(wk, wqkv0 + DD*DD, wqkv1 + DD*DD, DD*DD, DD);
    wsplit2<<<(DD*DD+255)/256, 256, 0, stream>>>(wv, wqkv0 + 2*DD*DD, wqkv1 + 2*DD*DD, DD*DD, DD);
    wsplit3<<<(DD*DD+255)/256, 256, 0, stream>>>(proj_w, wp0, wp1, wp2, DD*DD, DD);
    wsplit2<<<(DH*DD+255)/256, 256, 0, stream>>>(fc1_w, f10, f11, DH*DD, DD);
    wsplit2<<<(DD*DH+255)/256, 256, 0, stream>>>(fc2_w, f20, f21, DD*DH, DH);

    // LN1 -> swizzled split planes
    ln_split<0><<<RR/4, 256, 0, stream>>>(x, nullptr, ln1_g, ln1_b, A0, A1);

    // fused q/k/v GEMM (N=1536) + one refine
    gemm128<2,2,0,0,3><<<dim3(12, RR/128), 256, 0, stream>>>(
        A0, A1, nullptr, wqkv0, wqkv1, nullptr, nullptr, 1536, DD, 3e-4f,
        qs, ksp, vsp, nullptr, nullptr, nullptr, cnt + 0, list);
    refine_qkv<<<128, 256, 0, stream>>>(cnt + 0, list, x, ln1_g, ln1_b,
        wq, wk, wv, qs, ksp, vsp);

    // linear attention (exact), swizzled bf16 hi/lo output
    attn_kernel<<<T_STEPS * BB * 8, 256, 0, stream>>>(qs, ksp, vsp, Ah, Al);

    // proj GEMM (full 2x3 split: large |A|) + refine -> sp
    gemm128<2,3,0,0,1><<<dim3(4, RR/128), 256, 0, stream>>>(
        Ah, Al, nullptr, wp0, wp1, wp2, proj_b, DD, DD, 1e-3f,
        sp, nullptr, nullptr, nullptr, nullptr, nullptr, cnt + 1, list + LCAP);
    refine_proj<<<128, 256, 0, stream>>>(cnt + 1, list + LCAP, Ah, Al,
        proj_w, proj_b, sp);

    // LN2 of (x + sp) -> swizzled split planes
    ln_split<1><<<RR/4, 256, 0, stream>>>(x, sp, ln2_g, ln2_b, A0, A1);

    // fc1 GEMM + refine -> h spikes (aliases Ah/Al, safe after refine_proj)
    gemm128<2,2,0,0,1><<<dim3(16, RR/128), 256, 0, stream>>>(
        A0, A1, nullptr, f10, f11, nullptr, fc1_b, DH, DD, 3e-4f,
        hsp, nullptr, nullptr, nullptr, nullptr, nullptr, cnt + 2, list + 2*LCAP);
    refine_ln<<<128, 256, 0, stream>>>(cnt + 2, list + 2*LCAP, x, sp,
        ln2_g, ln2_b, fc1_w, fc1_b, DH, hsp);

    // fc2 GEMM (binary A, exact) + LIF + residuals -> fp32 out, then refine
    gemm128<1,2,1,2,1><<<dim3(4, RR/128), 256, 0, stream>>>(
        nullptr, nullptr, hsp, f20, f21, nullptr, fc2_b, DD, DH, 3e-4f,
        nullptr, nullptr, nullptr, outp, x, sp, cnt + 3, list + 3*LCAP);
    refine_out<<<128, 256, 0, stream>>>(cnt + 3, list + 3*LCAP, hsp,
        fc2_w, fc2_b, x, sp, outp);
}